// Round 7
// baseline (26180.869 us; speedup 1.0000x reference)
//
#include <hip/hip_runtime.h>
#include <math.h>

#define BB 32
#define TT 2048
#define FF 16
#define CC 17
#define HH 64

typedef float v2f __attribute__((ext_vector_type(2)));
typedef _Float16 h2 __attribute__((ext_vector_type(2)));

__device__ __forceinline__ float rlf(float v, int lane) {
    return __int_as_float(__builtin_amdgcn_readlane(__float_as_int(v), lane));
}
__device__ __forceinline__ int rli(int v, int lane) {
    return __builtin_amdgcn_readlane(v, lane);
}
__device__ __forceinline__ float uf(float v) {
    return __int_as_float(__builtin_amdgcn_readfirstlane(__float_as_int(v)));
}
__device__ __forceinline__ float ftanh(float x) {
    float e = __builtin_amdgcn_exp2f(x * 2.88539008177792681472f); // exp(2x)
    return 1.0f - 2.0f * __builtin_amdgcn_rcpf(e + 1.0f);
}
__device__ __forceinline__ float fdot2u(unsigned a, unsigned b, float c) {
    return __builtin_amdgcn_fdot2(__builtin_bit_cast(h2, a),
                                  __builtin_bit_cast(h2, b), c, false);
}
__device__ __forceinline__ unsigned packf16(float a, float b) {
    h2 p; p.x = (_Float16)a; p.y = (_Float16)b;   // RN, init-time only
    return __builtin_bit_cast(unsigned, p);
}
// LDS-only barrier: no vmcnt(0) drain.
__device__ __forceinline__ void bar_lds() {
    asm volatile("s_waitcnt lgkmcnt(0)\n\ts_barrier" ::: "memory");
}
#define PINV(v) asm volatile("" : "+v"(v))
#define PINA(v) asm volatile("" : "+a"(v))

// One block per batch element, 4 waves (1 wave/SIMD -> full 512-reg unified
// VGPR+AGPR budget). Every wave computes the ENTIRE hidden chain redundantly
// and fully in-wave (readlane broadcasts + f16 dot2; weights pinned in AGPRs)
// -- zero LDS, zero barriers for the hidden chain. Out layer: wave w owns
// columns 4w..4w+3 (f16 in arch VGPRs) + k-slice [16w,16w+16) of column 16.
// ONE barrier per G (pgq partial combine, parity double-buffered).
__attribute__((amdgpu_waves_per_eu(1, 1)))
__launch_bounds__(256)
__global__ void ncde_main(const float* __restrict__ x,
                          const float* __restrict__ wi1, const float* __restrict__ bi1,
                          const float* __restrict__ wi2, const float* __restrict__ bi2,
                          const float* __restrict__ w_in, const float* __restrict__ b_in,
                          const float* __restrict__ w_hid, const float* __restrict__ b_hid,
                          const float* __restrict__ w_out, const float* __restrict__ b_out,
                          float* __restrict__ zT)
{
    const int b   = blockIdx.x;
    const int tid = threadIdx.x;
    const int w   = tid >> 6;
    const int l   = tid & 63;

    __shared__ v2f pgq[2][4][64];   // (pg, a16) partials, parity double-buffered

    // ---- hidden weights: lane l owns column l, k packed in f16 pairs (AGPR) ----
    unsigned whp[4][32];
    #pragma unroll
    for (int j = 0; j < 32; ++j) {
        whp[0][j] = packf16(w_in[(2 * j) * HH + l],              w_in[(2 * j + 1) * HH + l]);
        whp[1][j] = packf16(w_hid[(0 * HH + 2 * j) * HH + l],    w_hid[(0 * HH + 2 * j + 1) * HH + l]);
        whp[2][j] = packf16(w_hid[(1 * HH + 2 * j) * HH + l],    w_hid[(1 * HH + 2 * j + 1) * HH + l]);
        whp[3][j] = packf16(w_hid[(2 * HH + 2 * j) * HH + l],    w_hid[(2 * HH + 2 * j + 1) * HH + l]);
    }
    float bh[4] = { b_in[l], b_hid[l], b_hid[HH + l], b_hid[2 * HH + l] };

    // ---- out-layer weights: 4 columns per wave + c16 k-slice (arch VGPRs) ----
    const int cb = 4 * w;
    unsigned wop[4][32];
    #pragma unroll
    for (int j = 0; j < 32; ++j) {
        #pragma unroll
        for (int i = 0; i < 4; ++i)
            wop[i][j] = packf16(w_out[(2 * j) * (CC * HH) + l * CC + cb + i],
                                w_out[(2 * j + 1) * (CC * HH) + l * CC + cb + i]);
    }
    unsigned w16p[8];
    #pragma unroll
    for (int jj = 0; jj < 8; ++jj)
        w16p[jj] = packf16(w_out[(16 * w + 2 * jj) * (CC * HH) + l * CC + 16],
                           w_out[(16 * w + 2 * jj + 1) * (CC * HH) + l * CC + 16]);
    float bo[4] = { b_out[l * CC + cb], b_out[l * CC + cb + 1],
                    b_out[l * CC + cb + 2], b_out[l * CC + cb + 3] };
    float bo16 = b_out[l * CC + 16];

    #pragma unroll
    for (int lay = 0; lay < 4; ++lay) {
        #pragma unroll
        for (int j = 0; j < 32; ++j) PINA(whp[lay][j]);
    }
    #pragma unroll
    for (int i = 0; i < 4; ++i) {
        #pragma unroll
        for (int j = 0; j < 32; ++j) PINV(wop[i][j]);
    }
    #pragma unroll
    for (int jj = 0; jj < 8; ++jj) PINV(w16p[jj]);

    // ---- z0 = relu(xa0 @ wi1 + bi1) @ wi2 + bi2 (computed identically by all waves) ----
    float z;
    {
        float h0 = bi1[l];
        #pragma unroll
        for (int c = 1; c < CC; ++c)
            h0 = fmaf(x[(size_t)b * TT * FF + (c - 1)], wi1[c * HH + l], h0);
        h0 = fmaxf(h0, 0.0f);
        z = bi2[l];
        #pragma unroll
        for (int k = 0; k < 64; ++k)
            z = fmaf(rlf(h0, k), wi2[k * HH + l], z);
    }
    if (w == 3) zT[(size_t)b * TT * HH + l] = z;

    // pack h*2^-8 into f16x2: every lane ends holding pair (l>>1)
    auto packb = [&](float hval) -> unsigned {
        float hs = hval * 0.00390625f;
        float pr = __shfl_xor(hs, 1);                 // DPP quad-perm pair swap
        float a  = (l & 1) ? pr : hs;
        float bb = (l & 1) ? hs : pr;
        return __builtin_bit_cast(unsigned, __builtin_amdgcn_cvt_pkrtz(a, bb));
    };

    // ---- g(zin, xd): fully in-wave hidden chain + split out layer ----
    auto G = [&](float zin, float xd0, float xd1, float xd2, float xd3,
                 float xd16, int pq) -> float {
        float cur = zin;
        #pragma unroll
        for (int lay = 0; lay < 4; ++lay) {
            unsigned hp = packb(cur);
            float a0 = 0.f, a1 = 0.f, a2 = 0.f, a3 = 0.f;
            #pragma unroll
            for (int j = 0; j < 32; j += 4) {
                int s0 = rli((int)hp, 2 * j);
                int s1 = rli((int)hp, 2 * j + 2);
                int s2 = rli((int)hp, 2 * j + 4);
                int s3 = rli((int)hp, 2 * j + 6);
                a0 = fdot2u((unsigned)s0, whp[lay][j],     a0);
                a1 = fdot2u((unsigned)s1, whp[lay][j + 1], a1);
                a2 = fdot2u((unsigned)s2, whp[lay][j + 2], a2);
                a3 = fdot2u((unsigned)s3, whp[lay][j + 3], a3);
            }
            cur = fmaxf(fmaf((a0 + a1) + (a2 + a3), 256.0f, bh[lay]), 0.0f);
        }
        unsigned hp = packb(cur);
        float u0 = 0.f, u1 = 0.f, u2 = 0.f, u3 = 0.f;
        #pragma unroll
        for (int j = 0; j < 32; ++j) {
            int s = rli((int)hp, 2 * j);
            u0 = fdot2u((unsigned)s, wop[0][j], u0);
            u1 = fdot2u((unsigned)s, wop[1][j], u1);
            u2 = fdot2u((unsigned)s, wop[2][j], u2);
            u3 = fdot2u((unsigned)s, wop[3][j], u3);
        }
        float a16 = 0.f;
        #pragma unroll
        for (int jj = 0; jj < 8; ++jj) {
            int s = rli((int)hp, 16 * w + 2 * jj);
            a16 = fdot2u((unsigned)s, w16p[jj], a16);
        }
        float t0 = ftanh(fmaf(u0, 256.0f, bo[0]));
        float t1 = ftanh(fmaf(u1, 256.0f, bo[1]));
        float t2 = ftanh(fmaf(u2, 256.0f, bo[2]));
        float t3 = ftanh(fmaf(u3, 256.0f, bo[3]));
        float pg = (t0 * xd0 + t1 * xd1) + (t2 * xd2 + t3 * xd3);
        pgq[pq][w][l] = (v2f){ pg, a16 };
        bar_lds();                                    // the ONLY barrier per G
        v2f s0 = pgq[pq][0][l], s1 = pgq[pq][1][l];
        v2f s2 = pgq[pq][2][l], s3 = pgq[pq][3][l];
        v2f st = (s0 + s1) + (s2 + s3);
        float u16 = fmaf(st.y, 256.0f, bo16);
        return fmaf(ftanh(u16), xd16, st.x);
    };

    // ---- time scan: wave w carries channels cb..cb+3 (+ shared ch16) ----
    const float* xb = x + (size_t)b * TT * FF;
    const int f0 = 4 * w - 1;            // feature of col cb (f<0 => time channel)

    float xp[4], dc[4], dp[4];
    float xp16, dc16, dp16;
    #pragma unroll
    for (int i = 0; i < 4; ++i) {
        int f = f0 + i;
        float v0 = (f < 0) ? 0.f : uf(xb[f]);
        float v1 = (f < 0) ? 0.f : uf(xb[FF + f]);
        dc[i] = (f < 0) ? 1.0f : (v1 - v0);
        dp[i] = dc[i];
        xp[i] = v1;
    }
    { float v0 = uf(xb[15]), v1 = uf(xb[FF + 15]);
      dc16 = v1 - v0; dp16 = dc16; xp16 = v1; }

    #pragma unroll 1
    for (int t = 0; t < TT - 1; ++t) {
        const float f43 = 4.0f / 3.0f;
        float x2[4];
        #pragma unroll
        for (int i = 0; i < 4; ++i) x2[i] = dp[i] + f43 * (dc[i] - dp[i]);
        float x216 = dp16 + f43 * (dc16 - dp16);

        int tn = (t + 2 < TT) ? (t + 2) : (TT - 1);
        float yn[4];
        #pragma unroll
        for (int i = 0; i < 4; ++i) {
            int f = f0 + i;
            yn[i] = (f < 0) ? 0.f : uf(xb[tn * FF + f]);
        }
        float yn16 = uf(xb[tn * FF + 15]);

        float k1 = G(z, dp[0], dp[1], dp[2], dp[3], dp16, 0);
        float k2 = G(z + k1 * (1.0f / 3.0f), dc[0], dc[1], dc[2], dc[3], dc16, 1);
        float k3 = G(z + (k2 - k1 * (1.0f / 3.0f)), x2[0], x2[1], x2[2], x2[3], x216, 0);
        float k4 = G(z + (k1 - k2 + k3), dc[0], dc[1], dc[2], dc[3], dc16, 1);
        z = z + 0.125f * (k1 + 3.0f * (k2 + k3) + k4);

        if (w == 3) zT[((size_t)b * TT + t + 1) * HH + l] = z;

        #pragma unroll
        for (int i = 0; i < 4; ++i) {
            dp[i] = dc[i];
            dc[i] = (f0 + i < 0) ? 1.0f : (yn[i] - xp[i]);
            xp[i] = yn[i];
        }
        dp16 = dc16; dc16 = yn16 - xp16; xp16 = yn16;
    }
}

// out = gelu_exact(zT) @ w_proj + b_proj ; mask = 0
__global__ void ncde_proj(const float* __restrict__ zT,
                          const float* __restrict__ w_proj, const float* __restrict__ b_proj,
                          float* __restrict__ out, float* __restrict__ mask)
{
    __shared__ float gz[16][64];
    const int blk = blockIdx.x;
    const int tid = threadIdx.x;
    const int r16 = tid >> 4, f = tid & 15;
    const int row0 = blk * 16;

    #pragma unroll
    for (int i = 0; i < 4; ++i) {
        int idx = tid + i * 256;
        int r = idx >> 6, k = idx & 63;
        float zv = zT[(size_t)(row0 + r) * HH + k];
        gz[r][k] = 0.5f * zv * (1.0f + erff(zv * 0.70710678118654752f));
    }
    __syncthreads();

    float acc = b_proj[f];
    #pragma unroll
    for (int k = 0; k < 64; ++k)
        acc = fmaf(gz[r16][k], w_proj[k * FF + f], acc);
    out[(size_t)(row0 + r16) * FF + f] = acc;
    if (f == 0) mask[row0 + r16] = 0.0f;
}

extern "C" void kernel_launch(void* const* d_in, const int* in_sizes, int n_in,
                              void* d_out, int out_size, void* d_ws, size_t ws_size,
                              hipStream_t stream)
{
    (void)in_sizes; (void)n_in; (void)d_ws; (void)ws_size; (void)out_size;
    const float* x      = (const float*)d_in[0];
    const float* wi1    = (const float*)d_in[1];
    const float* bi1    = (const float*)d_in[2];
    const float* wi2    = (const float*)d_in[3];
    const float* bi2    = (const float*)d_in[4];
    const float* w_in   = (const float*)d_in[5];
    const float* b_in   = (const float*)d_in[6];
    const float* w_hid  = (const float*)d_in[7];
    const float* b_hid  = (const float*)d_in[8];
    const float* w_out  = (const float*)d_in[9];
    const float* b_out  = (const float*)d_in[10];
    const float* w_proj = (const float*)d_in[11];
    const float* b_proj = (const float*)d_in[12];

    float* zT   = (float*)d_out;                       // B*T*H
    float* outp = zT + (size_t)BB * TT * HH;           // B*T*F
    float* mask = outp + (size_t)BB * TT * FF;         // B*T

    ncde_main<<<dim3(BB), dim3(256), 0, stream>>>(
        x, wi1, bi1, wi2, bi2, w_in, b_in, w_hid, b_hid, w_out, b_out, zT);
    ncde_proj<<<dim3((BB * TT) / 16), dim3(256), 0, stream>>>(
        zT, w_proj, b_proj, outp, mask);
}

// Round 8
// 13118.793 us; speedup vs baseline: 1.9957x; 1.9957x over previous
//
#include <hip/hip_runtime.h>
#include <math.h>

#define BB 32
#define TT 2048
#define FF 16
#define CC 17
#define HH 64

typedef float v2f __attribute__((ext_vector_type(2)));
typedef _Float16 h2 __attribute__((ext_vector_type(2)));

__device__ __forceinline__ float rl(float v, int lane) {
    return __int_as_float(__builtin_amdgcn_readlane(__float_as_int(v), lane));
}
__device__ __forceinline__ int rli(int v, int lane) {
    return __builtin_amdgcn_readlane(v, lane);
}
__device__ __forceinline__ float uf(float v) {
    return __int_as_float(__builtin_amdgcn_readfirstlane(__float_as_int(v)));
}
__device__ __forceinline__ float ftanh(float x) {
    float e = __builtin_amdgcn_exp2f(x * 2.88539008177792681472f); // exp(2x)
    return 1.0f - 2.0f * __builtin_amdgcn_rcpf(e + 1.0f);
}
__device__ __forceinline__ float fdot2u(unsigned a, unsigned b, float c) {
    return __builtin_amdgcn_fdot2(__builtin_bit_cast(h2, a),
                                  __builtin_bit_cast(h2, b), c, false);
}
__device__ __forceinline__ unsigned packf16(float a, float b) {
    h2 p; p.x = (_Float16)a; p.y = (_Float16)b;   // RN, init-time only
    return __builtin_bit_cast(unsigned, p);
}
// LDS-only barrier: no vmcnt(0) drain.
__device__ __forceinline__ void bar_lds() {
    asm volatile("s_waitcnt lgkmcnt(0)\n\ts_barrier" ::: "memory");
}
#define PIN(v) asm volatile("" : "+v"(v))

// R3 structure (best: 13.28ms) minus the h-publish barrier segment:
// after the 4th hidden combine EVERY wave holds full h (lane l = h[l]), so the
// out layer packs h->f16 in-wave (shfl_xor+cvt_pkrtz) and broadcasts via
// v_readlane into v_dot2_f32_f16. 5 barrier segments per G instead of 6,
// and the out weights are 68 packed-f16 regs instead of 128 f32.
__attribute__((amdgpu_waves_per_eu(2, 2)))
__launch_bounds__(512)
__global__ void ncde_main(const float* __restrict__ x,
                          const float* __restrict__ wi1, const float* __restrict__ bi1,
                          const float* __restrict__ wi2, const float* __restrict__ bi2,
                          const float* __restrict__ w_in, const float* __restrict__ b_in,
                          const float* __restrict__ w_hid, const float* __restrict__ b_hid,
                          const float* __restrict__ w_out, const float* __restrict__ b_out,
                          float* __restrict__ zT)
{
    const int b   = blockIdx.x;
    const int tid = threadIdx.x;
    const int w   = tid >> 6;
    const int l   = tid & 63;

    __shared__ float ph[4][8][64];   // hidden partials [layer][wave][h]
    __shared__ v2f  pgq[8][64];      // (pg, a16) partials per wave

    // ---- hidden weights in registers (R3 layout: wave w owns k-slice 8w..8w+8) ----
    float whid[4][8];
    #pragma unroll
    for (int kk = 0; kk < 8; ++kk) {
        int k = 8 * w + kk;
        whid[0][kk] = w_in[k * HH + l];
        whid[1][kk] = w_hid[(0 * HH + k) * HH + l];
        whid[2][kk] = w_hid[(1 * HH + k) * HH + l];
        whid[3][kk] = w_hid[(2 * HH + k) * HH + l];
    }
    float bfold[4];
    bfold[0] = (w == 0) ? b_in[l] : 0.0f;
    bfold[1] = (w == 0) ? b_hid[0 * HH + l] : 0.0f;
    bfold[2] = (w == 0) ? b_hid[1 * HH + l] : 0.0f;
    bfold[3] = (w == 0) ? b_hid[2 * HH + l] : 0.0f;

    // ---- out-layer weights, f16-packed over k pairs ----
    const int c0 = 2 * w, c1 = 2 * w + 1;
    unsigned wo0p[32], wo1p[32], w16p[4];
    #pragma unroll
    for (int j = 0; j < 32; ++j) {
        wo0p[j] = packf16(w_out[(2 * j) * (CC * HH) + l * CC + c0],
                          w_out[(2 * j + 1) * (CC * HH) + l * CC + c0]);
        wo1p[j] = packf16(w_out[(2 * j) * (CC * HH) + l * CC + c1],
                          w_out[(2 * j + 1) * (CC * HH) + l * CC + c1]);
    }
    #pragma unroll
    for (int jj = 0; jj < 4; ++jj)
        w16p[jj] = packf16(w_out[(8 * w + 2 * jj) * (CC * HH) + l * CC + 16],
                           w_out[(8 * w + 2 * jj + 1) * (CC * HH) + l * CC + 16]);
    float bo0  = b_out[l * CC + c0];
    float bo1  = b_out[l * CC + c1];
    float bo16 = b_out[l * CC + 16];

    #pragma unroll
    for (int j = 0; j < 32; ++j) { PIN(wo0p[j]); PIN(wo1p[j]); }
    #pragma unroll
    for (int jj = 0; jj < 4; ++jj) PIN(w16p[jj]);
    #pragma unroll
    for (int i = 0; i < 4; ++i) { PIN(bfold[i]); }
    PIN(bo0); PIN(bo1); PIN(bo16);

    // ---- z0 = relu(xa0 @ wi1 + bi1) @ wi2 + bi2 ----
    float z;
    {
        float h0 = bi1[l];
        #pragma unroll
        for (int c = 1; c < CC; ++c)
            h0 = fmaf(x[(size_t)b * TT * FF + (c - 1)], wi1[c * HH + l], h0);
        h0 = fmaxf(h0, 0.0f);
        z = bi2[l];
        #pragma unroll
        for (int k = 0; k < 64; ++k)
            z = fmaf(rl(h0, k), wi2[k * HH + l], z);
    }
    if (w == 0) zT[(size_t)b * TT * HH + l] = z;

    // pack h*2^-8 into f16x2: every lane ends holding pair (h[2j],h[2j+1]), j=l>>1
    auto packb = [&](float hval) -> unsigned {
        float hs = hval * 0.00390625f;
        float pr = __shfl_xor(hs, 1);
        float a  = (l & 1) ? pr : hs;
        float bb = (l & 1) ? hs : pr;
        return __builtin_bit_cast(unsigned, __builtin_amdgcn_cvt_pkrtz(a, bb));
    };

    // ---- g(zin, xd) ----
    auto G = [&](float zin, float xd0, float xd1, float xd16) -> float {
        float cur = zin;
        #pragma unroll
        for (int layer = 0; layer < 4; ++layer) {
            float a0 = bfold[layer], a1 = 0.0f;
            #pragma unroll
            for (int kk = 0; kk < 8; kk += 2) {
                float s0 = rl(cur, 8 * w + kk);
                float s1 = rl(cur, 8 * w + kk + 1);
                a0 = fmaf(s0, whid[layer][kk],     a0);
                a1 = fmaf(s1, whid[layer][kk + 1], a1);
            }
            ph[layer][w][l] = a0 + a1;
            bar_lds();
            float r0 = ph[layer][0][l], r1 = ph[layer][1][l];
            float r2 = ph[layer][2][l], r3 = ph[layer][3][l];
            float r4 = ph[layer][4][l], r5 = ph[layer][5][l];
            float r6 = ph[layer][6][l], r7 = ph[layer][7][l];
            cur = fmaxf(((r0 + r1) + (r2 + r3)) + ((r4 + r5) + (r6 + r7)), 0.0f);
        }
        // out layer, fully in-wave from cur (every wave holds full h)
        unsigned hp = packb(cur);
        float u0a = 0.f, u0b = 0.f, u1a = 0.f, u1b = 0.f;
        #pragma unroll
        for (int j = 0; j < 32; j += 2) {
            unsigned s0 = (unsigned)rli((int)hp, 2 * j);
            unsigned s1 = (unsigned)rli((int)hp, 2 * j + 2);
            u0a = fdot2u(s0, wo0p[j],     u0a);
            u1a = fdot2u(s0, wo1p[j],     u1a);
            u0b = fdot2u(s1, wo0p[j + 1], u0b);
            u1b = fdot2u(s1, wo1p[j + 1], u1b);
        }
        // c=16 column, this wave's k-slice (pairs 4w..4w+3 -> lanes 8w+2jj)
        float a16a = 0.f, a16b = 0.f;
        #pragma unroll
        for (int jj = 0; jj < 4; jj += 2) {
            unsigned s0 = (unsigned)rli((int)hp, 8 * w + 2 * jj);
            unsigned s1 = (unsigned)rli((int)hp, 8 * w + 2 * jj + 2);
            a16a = fdot2u(s0, w16p[jj],     a16a);
            a16b = fdot2u(s1, w16p[jj + 1], a16b);
        }
        float u0 = fmaf(u0a + u0b, 256.0f, bo0);
        float u1 = fmaf(u1a + u1b, 256.0f, bo1);
        float pg = ftanh(u0) * xd0 + ftanh(u1) * xd1;
        pgq[w][l] = (v2f){ pg, a16a + a16b };
        bar_lds();
        v2f s0 = pgq[0][l], s1 = pgq[1][l], s2 = pgq[2][l], s3 = pgq[3][l];
        v2f s4 = pgq[4][l], s5 = pgq[5][l], s6 = pgq[6][l], s7 = pgq[7][l];
        v2f st = ((s0 + s1) + (s2 + s3)) + ((s4 + s5) + (s6 + s7));
        float u16 = fmaf(st.y, 256.0f, bo16);
        return fmaf(ftanh(u16), xd16, st.x);
    };

    // ---- time scan (uniform x scalars in SGPRs) ----
    const float* xb = x + (size_t)b * TT * FF;
    const bool hasc0 = (w != 0);
    const int  f0 = 2 * w - 1;
    const int  f1 = 2 * w;
    float xp0  = hasc0 ? uf(xb[f0]) : 0.0f;
    float xp1  = uf(xb[f1]);
    float xp16 = uf(xb[15]);
    float xn0  = hasc0 ? uf(xb[FF + f0]) : 0.0f;
    float xn1  = uf(xb[FF + f1]);
    float xn16 = uf(xb[FF + 15]);
    float dc0  = hasc0 ? (xn0 - xp0) : 1.0f;
    float dc1  = xn1 - xp1;
    float dc16 = xn16 - xp16;
    float dp0 = dc0, dp1 = dc1, dp16 = dc16;
    xp0 = xn0; xp1 = xn1; xp16 = xn16;

    #pragma unroll 1
    for (int t = 0; t < TT - 1; ++t) {
        const float f43 = 4.0f / 3.0f;
        float x20  = dp0  + f43 * (dc0  - dp0);
        float x21  = dp1  + f43 * (dc1  - dp1);
        float x216 = dp16 + f43 * (dc16 - dp16);

        int tn = (t + 2 < TT) ? (t + 2) : (TT - 1);
        float yn0  = hasc0 ? uf(xb[tn * FF + f0]) : 0.0f;
        float yn1  = uf(xb[tn * FF + f1]);
        float yn16 = uf(xb[tn * FF + 15]);

        float k1 = G(z, dp0, dp1, dp16);
        float k2 = G(z + k1 * (1.0f / 3.0f), dc0, dc1, dc16);
        float k3 = G(z + (k2 - k1 * (1.0f / 3.0f)), x20, x21, x216);
        float k4 = G(z + (k1 - k2 + k3), dc0, dc1, dc16);
        z = z + 0.125f * (k1 + 3.0f * (k2 + k3) + k4);

        if (w == 0) zT[((size_t)b * TT + t + 1) * HH + l] = z;

        dp0 = dc0; dp1 = dc1; dp16 = dc16;
        dc0 = hasc0 ? (yn0 - xp0) : 1.0f;
        dc1 = yn1 - xp1;
        dc16 = yn16 - xp16;
        xp0 = yn0; xp1 = yn1; xp16 = yn16;
    }
}

// out = gelu_exact(zT) @ w_proj + b_proj ; mask = 0
__global__ void ncde_proj(const float* __restrict__ zT,
                          const float* __restrict__ w_proj, const float* __restrict__ b_proj,
                          float* __restrict__ out, float* __restrict__ mask)
{
    __shared__ float gz[16][64];
    const int blk = blockIdx.x;
    const int tid = threadIdx.x;
    const int r16 = tid >> 4, f = tid & 15;
    const int row0 = blk * 16;

    #pragma unroll
    for (int i = 0; i < 4; ++i) {
        int idx = tid + i * 256;
        int r = idx >> 6, k = idx & 63;
        float zv = zT[(size_t)(row0 + r) * HH + k];
        gz[r][k] = 0.5f * zv * (1.0f + erff(zv * 0.70710678118654752f));
    }
    __syncthreads();

    float acc = b_proj[f];
    #pragma unroll
    for (int k = 0; k < 64; ++k)
        acc = fmaf(gz[r16][k], w_proj[k * FF + f], acc);
    out[(size_t)(row0 + r16) * FF + f] = acc;
    if (f == 0) mask[row0 + r16] = 0.0f;
}

extern "C" void kernel_launch(void* const* d_in, const int* in_sizes, int n_in,
                              void* d_out, int out_size, void* d_ws, size_t ws_size,
                              hipStream_t stream)
{
    (void)in_sizes; (void)n_in; (void)d_ws; (void)ws_size; (void)out_size;
    const float* x      = (const float*)d_in[0];
    const float* wi1    = (const float*)d_in[1];
    const float* bi1    = (const float*)d_in[2];
    const float* wi2    = (const float*)d_in[3];
    const float* bi2    = (const float*)d_in[4];
    const float* w_in   = (const float*)d_in[5];
    const float* b_in   = (const float*)d_in[6];
    const float* w_hid  = (const float*)d_in[7];
    const float* b_hid  = (const float*)d_in[8];
    const float* w_out  = (const float*)d_in[9];
    const float* b_out  = (const float*)d_in[10];
    const float* w_proj = (const float*)d_in[11];
    const float* b_proj = (const float*)d_in[12];

    float* zT   = (float*)d_out;                       // B*T*H
    float* outp = zT + (size_t)BB * TT * HH;           // B*T*F
    float* mask = outp + (size_t)BB * TT * FF;         // B*T

    ncde_main<<<dim3(BB), dim3(512), 0, stream>>>(
        x, wi1, bi1, wi2, bi2, w_in, b_in, w_hid, b_hid, w_out, b_out, zT);
    ncde_proj<<<dim3((BB * TT) / 16), dim3(256), 0, stream>>>(
        zT, w_proj, b_proj, outp, mask);
}